// Round 3
// baseline (253.516 us; speedup 1.0000x reference)
//
#include <hip/hip_runtime.h>
#include <hip/hip_bf16.h>
#include <math.h>

#define B_ 8
#define S_ 2048
#define D_ 1024
#define H_ 64
#define M_ (B_*S_)
#define SPLIT 4
#define KPS (S_/SPLIT)   // 512 keys per split

typedef __attribute__((ext_vector_type(8))) short bf16x8;
typedef __attribute__((ext_vector_type(8))) unsigned short u16x8;
typedef __attribute__((ext_vector_type(4))) float f32x4;

__device__ inline unsigned short f2bf(float f) {
    unsigned int u = __builtin_bit_cast(unsigned int, f);
    u += 0x7fffu + ((u >> 16) & 1u);   // round-to-nearest-even
    return (unsigned short)(u >> 16);
}

// async global->LDS, 16B per lane (global side carries the bank swizzle).
__device__ inline void async16(const void* g, void* l) {
    __builtin_amdgcn_global_load_lds((const __attribute__((address_space(1))) void*)g,
                                     (__attribute__((address_space(3))) void*)l, 16, 0, 0);
}

// mask -> multiplicative 1.0/0.0. Layout sniff: jax bool may be 1-byte or int32.
__global__ __launch_bounds__(256) void mask_kernel(const unsigned char* __restrict__ mask,
                                                   float* __restrict__ mmul, int n) {
    int j = blockIdx.x * 256 + threadIdx.x;
    if (j >= n) return;
    bool boolLayout = mask[1] != 0;
    int mv = boolLayout ? (int)mask[j] : ((const int*)mask)[j];
    mmul[j] = mv ? 1.0f : 0.0f;
}

// Transpose W[1024][64] fp32 -> Wt[64][1024] bf16, one matrix per blockIdx.y.
__global__ __launch_bounds__(256) void wprep_kernel(
    const float* __restrict__ Wq, const float* __restrict__ Wk, const float* __restrict__ Wv,
    unsigned short* __restrict__ Wt)
{
    const int m = blockIdx.y;
    const float* W = (m == 0) ? Wq : (m == 1) ? Wk : Wv;
    unsigned short* Wo = Wt + (size_t)m * 64 * 1024;
    __shared__ unsigned short T[64][65];
    const int t = threadIdx.x;
    const int k0 = blockIdx.x * 64;
    #pragma unroll
    for (int i = 0; i < 16; i++) {
        int vi = t + i * 256;
        int kk = vi >> 6, n = vi & 63;
        T[kk][n] = f2bf(W[(size_t)(k0 + kk) * 64 + n]);
    }
    __syncthreads();
    #pragma unroll
    for (int i = 0; i < 4; i++) {
        int vi = t + i * 256;
        int n = vi >> 4, k4 = vi & 15;
        ushort4 u;
        u.x = T[k4*4+0][n]; u.y = T[k4*4+1][n]; u.z = T[k4*4+2][n]; u.w = T[k4*4+3][n];
        *(ushort4*)&Wo[(size_t)n * 1024 + k0 + k4*4] = u;
    }
}

// x[M,1024] @ W[1024,64], barrier-free register GEMM with explicit
// 4-deep software-pipelined register prefetch.
// Round-1 post-mortem: without explicit stages the compiler allocated 44
// VGPRs and kept ~1 iteration of loads in flight -> latency-bound at
// 1.2 TB/s. Here each stage holds A(8)+B(16) VGPRs; depth 4 keeps ~24
// loads in flight per wave, enough to cover L3/HBM latency at the
// grid-limited 3 waves/SIMD. Outer loop x4, inner 8 iterations unrolled:
// stage index (it & 3) is compile-time so stages stay in registers
// (rule: runtime-indexed register arrays spill to scratch).
__global__ __launch_bounds__(256) void proj_kernel(
    const float* __restrict__ q, const float* __restrict__ kx, const float* __restrict__ vx,
    const unsigned short* __restrict__ Wt,
    unsigned short* __restrict__ qp, unsigned short* __restrict__ kp, unsigned short* __restrict__ vpT)
{
    const int m = blockIdx.y;
    const float* x = (m == 0) ? q : (m == 1) ? kx : vx;
    const unsigned short* Wm = Wt + (size_t)m * 64 * 1024;

    const int t = threadIdx.x;
    const int w = t >> 6, l = t & 63;
    const int lrow = l & 15, quad = l >> 4;
    const int row0 = blockIdx.x * 64;

    // A: row = row0 + w*16 + lrow, k-offset quad*8 within each 32-chunk
    const float* xa = x + (size_t)(row0 + w * 16 + lrow) * D_ + quad * 8;
    // B: col n = c*16 + lrow of Wt, same k-offset
    const unsigned short* wb = Wm + (size_t)lrow * D_ + quad * 8;

    f32x4 acc[4] = {};

    constexpr int PF = 4;                 // pipeline depth
    f32x4  pa0[PF], pa1[PF];
    bf16x8 pb0[PF], pb1[PF], pb2[PF], pb3[PF];

    #pragma unroll
    for (int i = 0; i < PF; i++) {        // prologue: fill all stages
        const int k = i * 32;
        pa0[i] = *(const f32x4*)(xa + k);
        pa1[i] = *(const f32x4*)(xa + k + 4);
        pb0[i] = *(const bf16x8*)(wb + k);
        pb1[i] = *(const bf16x8*)(wb + 16 * D_ + k);
        pb2[i] = *(const bf16x8*)(wb + 32 * D_ + k);
        pb3[i] = *(const bf16x8*)(wb + 48 * D_ + k);
    }

    #pragma unroll 1
    for (int ob = 0; ob < 4; ob++) {
        #pragma unroll                    // inner unroll: st compile-time
        for (int ii = 0; ii < 8; ii++) {
            const int it = ob * 8 + ii;
            const int st = ii & (PF - 1);
            f32x4  a0 = pa0[st], a1 = pa1[st];
            bf16x8 b0 = pb0[st], b1 = pb1[st], b2 = pb2[st], b3 = pb3[st];
            if (it + PF < 32) {           // refill this stage PF iters ahead
                const int k = (it + PF) * 32;
                pa0[st] = *(const f32x4*)(xa + k);
                pa1[st] = *(const f32x4*)(xa + k + 4);
                pb0[st] = *(const bf16x8*)(wb + k);
                pb1[st] = *(const bf16x8*)(wb + 16 * D_ + k);
                pb2[st] = *(const bf16x8*)(wb + 32 * D_ + k);
                pb3[st] = *(const bf16x8*)(wb + 48 * D_ + k);
            }
            bf16x8 af;
            af[0] = (short)f2bf(a0.x); af[1] = (short)f2bf(a0.y);
            af[2] = (short)f2bf(a0.z); af[3] = (short)f2bf(a0.w);
            af[4] = (short)f2bf(a1.x); af[5] = (short)f2bf(a1.y);
            af[6] = (short)f2bf(a1.z); af[7] = (short)f2bf(a1.w);
            acc[0] = __builtin_amdgcn_mfma_f32_16x16x32_bf16(af, b0, acc[0], 0, 0, 0);
            acc[1] = __builtin_amdgcn_mfma_f32_16x16x32_bf16(af, b1, acc[1], 0, 0, 0);
            acc[2] = __builtin_amdgcn_mfma_f32_16x16x32_bf16(af, b2, acc[2], 0, 0, 0);
            acc[3] = __builtin_amdgcn_mfma_f32_16x16x32_bf16(af, b3, acc[3], 0, 0, 0);
        }
    }

    const int orow = row0 + w * 16 + quad * 4;
    if (m < 2) {
        unsigned short* outp = (m == 0) ? qp : kp;
        const float sc = (m == 0) ? 0.125f : 1.0f;   // fold attn scale into qp
        #pragma unroll
        for (int c = 0; c < 4; c++)
            #pragma unroll
            for (int rr = 0; rr < 4; rr++)
                outp[(size_t)(orow + rr) * H_ + c * 16 + lrow] = f2bf(acc[c][rr] * sc);
    } else {
        // vpT[b][h][s], s0..s0+3 contiguous per lane -> 8B stores
        const int bb = orow >> 11;
        const int s0 = orow & (S_ - 1);
        #pragma unroll
        for (int c = 0; c < 4; c++) {
            ushort4 u;
            u.x = f2bf(acc[c][0]); u.y = f2bf(acc[c][1]);
            u.z = f2bf(acc[c][2]); u.w = f2bf(acc[c][3]);
            *(ushort4*)&vpT[((size_t)bb * H_ + c * 16 + lrow) * S_ + s0] = u;
        }
    }
}

// Flash attention partial: block = (q-tile 64, batch, key-split). Max-free
// single-pass exp => partials over disjoint key ranges combine by addition.
// K and V^T tiles async-staged (L2-resident -> cheap barrier drain).
__global__ __launch_bounds__(256) void attn_kernel(
    const unsigned short* __restrict__ qp, const unsigned short* __restrict__ kp,
    const unsigned short* __restrict__ vpT, const float* __restrict__ mmul,
    float* __restrict__ po, float* __restrict__ pl)
{
    __shared__ unsigned short Qs[64][72];
    __shared__ unsigned short Ps[64][72];
    __shared__ unsigned short Ks[64 * 64];   // swizzled chunks [key][h]
    __shared__ unsigned short Vt[64 * 64];   // swizzled chunks [h][key]

    const int t = threadIdx.x;
    const int w = t >> 6, l = t & 63;
    const int lrow = l & 15, quad = l >> 4;
    const int b = blockIdx.y, q0 = blockIdx.x * 64, split = blockIdx.z;
    const int key0 = split * KPS;
    const size_t basebs = (size_t)b * S_;
    const unsigned short* vb = vpT + (size_t)b * H_ * S_;

    #pragma unroll
    for (int i = 0; i < 2; i++) {            // Q tile once: 512 16B-chunks
        int p = t + i * 256;
        int r = p >> 3, c8 = p & 7;
        u16x8 u = *(const u16x8*)&qp[(basebs + q0 + r) * H_ + c8 * 8];
        *(u16x8*)&Qs[r][c8 * 8] = u;
    }

    float lsum[4] = {0.f, 0.f, 0.f, 0.f};
    f32x4 o[4] = {};

    for (int kt = 0; kt < KPS / 64; kt++) {
        const int k0 = key0 + kt * 64;
        __syncthreads();                     // prev tile's LDS reads done
        #pragma unroll
        for (int j = 0; j < 2; j++) {        // K tile: 512 chunks
            int p = (w * 2 + j) * 64 + l;
            int r = p >> 3;
            int c8 = (p & 7) ^ (r & 7);
            async16(&kp[(basebs + k0 + r) * H_ + c8 * 8], &Ks[p * 8]);
        }
        #pragma unroll
        for (int j = 0; j < 2; j++) {        // V^T tile: 512 chunks
            int p = (w * 2 + j) * 64 + l;
            int h = p >> 3;
            int c8 = (p & 7) ^ (h & 7);
            async16(&vb[(size_t)h * S_ + k0 + c8 * 8], &Vt[p * 8]);
        }
        float mm[4];
        #pragma unroll
        for (int c = 0; c < 4; c++) mm[c] = mmul[basebs + k0 + c*16 + lrow];
        __syncthreads();                     // drain async queue

        // S = Q K^T (pre-scaled by 1/8 via qp)
        f32x4 s[4] = {};
        #pragma unroll
        for (int kk = 0; kk < 2; kk++) {
            bf16x8 aq = *(const bf16x8*)&Qs[w*16 + lrow][kk*32 + quad*8];
            #pragma unroll
            for (int c = 0; c < 4; c++) {
                const int n = c*16 + lrow;
                bf16x8 bk = *(const bf16x8*)&Ks[(n * 8 + ((kk*4 + quad) ^ (n & 7))) * 8];
                s[c] = __builtin_amdgcn_mfma_f32_16x16x32_bf16(aq, bk, s[c], 0, 0, 0);
            }
        }
        // single-pass softmax numerator; sum deferred
        #pragma unroll
        for (int r = 0; r < 4; r++) {
            float p0 = __expf(s[0][r]) * mm[0];
            float p1 = __expf(s[1][r]) * mm[1];
            float p2 = __expf(s[2][r]) * mm[2];
            float p3 = __expf(s[3][r]) * mm[3];
            lsum[r] += (p0 + p1) + (p2 + p3);
            const int pr = w*16 + quad*4 + r;
            Ps[pr][ 0 + lrow] = f2bf(p0);
            Ps[pr][16 + lrow] = f2bf(p1);
            Ps[pr][32 + lrow] = f2bf(p2);
            Ps[pr][48 + lrow] = f2bf(p3);
        }
        // Ps rows [w*16, w*16+16) wave-local: no barrier needed
        #pragma unroll
        for (int kk = 0; kk < 2; kk++) {
            bf16x8 ap = *(const bf16x8*)&Ps[w*16 + lrow][kk*32 + quad*8];
            #pragma unroll
            for (int c = 0; c < 4; c++) {
                const int h = c*16 + lrow;
                bf16x8 bv = *(const bf16x8*)&Vt[(h * 8 + ((kk*4 + quad) ^ (h & 7))) * 8];
                o[c] = __builtin_amdgcn_mfma_f32_16x16x32_bf16(ap, bv, o[c], 0, 0, 0);
            }
        }
    }

    float* pob = po + (size_t)split * M_ * H_;
    float* plb = pl + (size_t)split * M_;
    #pragma unroll
    for (int r = 0; r < 4; r++) {
        #pragma unroll
        for (int d = 1; d < 16; d <<= 1)
            lsum[r] += __shfl_xor(lsum[r], d, 64);
        const size_t row = basebs + q0 + w*16 + quad*4 + r;
        if (lrow == 0) plb[row] = lsum[r];
        #pragma unroll
        for (int c = 0; c < 4; c++)
            pob[row * H_ + c*16 + lrow] = o[c][r];
    }
}

// out = (sum_s po[s]) / (sum_s pl[s]); one float4 per thread.
__global__ __launch_bounds__(256) void combine_kernel(
    const float* __restrict__ po, const float* __restrict__ pl, float* __restrict__ out)
{
    const int idx = blockIdx.x * 256 + threadIdx.x;
    const size_t row = idx >> 4;
    const int c4 = (idx & 15) * 4;
    float lt = 0.f;
    #pragma unroll
    for (int s = 0; s < SPLIT; s++) lt += pl[(size_t)s * M_ + row];
    f32x4 acc = {};
    #pragma unroll
    for (int s = 0; s < SPLIT; s++) {
        const f32x4 p = *(const f32x4*)&po[((size_t)s * M_ + row) * H_ + c4];
        acc += p;
    }
    const float inv = 1.0f / lt;
    f32x4 r = acc * inv;
    *(f32x4*)&out[row * H_ + c4] = r;
}

extern "C" void kernel_launch(void* const* d_in, const int* in_sizes, int n_in,
                              void* d_out, int out_size, void* d_ws, size_t ws_size,
                              hipStream_t stream) {
    const float* q  = (const float*)d_in[0];
    const float* k  = (const float*)d_in[1];
    const float* v  = (const float*)d_in[2];
    const unsigned char* mask = (const unsigned char*)d_in[3];
    const float* Wq = (const float*)d_in[4];
    const float* Wk = (const float*)d_in[5];
    const float* Wv = (const float*)d_in[6];
    float* out = (float*)d_out;

    unsigned short* qp  = (unsigned short*)d_ws;         // 2 MB
    unsigned short* kp  = qp + (size_t)M_ * H_;          // 2 MB
    unsigned short* vpT = kp + (size_t)M_ * H_;          // 2 MB, [b][h][s]
    float* mmul = (float*)(vpT + (size_t)M_ * H_);       // 64 KB
    unsigned short* Wt = (unsigned short*)(mmul + M_);   // 384 KB
    float* po = (float*)(Wt + (size_t)3 * 64 * 1024);    // 16.8 MB
    float* pl = po + (size_t)SPLIT * M_ * H_;            // 256 KB

    wprep_kernel<<<dim3(16, 3), dim3(256), 0, stream>>>(Wq, Wk, Wv, Wt);
    mask_kernel<<<dim3((M_ + 255)/256), dim3(256), 0, stream>>>(mask, mmul, M_);
    proj_kernel<<<dim3(M_/64, 3), dim3(256), 0, stream>>>(q, k, v, Wt, qp, kp, vpT);
    attn_kernel<<<dim3(S_/64, B_, SPLIT), dim3(256), 0, stream>>>(qp, kp, vpT, mmul, po, pl);
    combine_kernel<<<dim3(M_*16/256), dim3(256), 0, stream>>>(po, pl, out);
}

// Round 4
// 243.232 us; speedup vs baseline: 1.0423x; 1.0423x over previous
//
#include <hip/hip_runtime.h>
#include <hip/hip_bf16.h>
#include <math.h>

#define B_ 8
#define S_ 2048
#define D_ 1024
#define H_ 64
#define M_ (B_*S_)
#define SPLIT 4
#define KPS (S_/SPLIT)   // 512 keys per split

typedef __attribute__((ext_vector_type(8))) short bf16x8;
typedef __attribute__((ext_vector_type(8))) unsigned short u16x8;
typedef __attribute__((ext_vector_type(4))) float f32x4;

__device__ inline unsigned short f2bf(float f) {
    unsigned int u = __builtin_bit_cast(unsigned int, f);
    u += 0x7fffu + ((u >> 16) & 1u);   // round-to-nearest-even
    return (unsigned short)(u >> 16);
}

// async global->LDS, 16B per lane (global side carries the bank swizzle).
__device__ inline void async16(const void* g, void* l) {
    __builtin_amdgcn_global_load_lds((const __attribute__((address_space(1))) void*)g,
                                     (__attribute__((address_space(3))) void*)l, 16, 0, 0);
}

// mask -> multiplicative 1.0/0.0. Layout sniff: jax bool may be 1-byte or int32.
__global__ __launch_bounds__(256) void mask_kernel(const unsigned char* __restrict__ mask,
                                                   float* __restrict__ mmul, int n) {
    int j = blockIdx.x * 256 + threadIdx.x;
    if (j >= n) return;
    bool boolLayout = mask[1] != 0;
    int mv = boolLayout ? (int)mask[j] : ((const int*)mask)[j];
    mmul[j] = mv ? 1.0f : 0.0f;
}

// Transpose W[1024][64] fp32 -> Wt[64][1024] bf16, one matrix per blockIdx.y.
__global__ __launch_bounds__(256) void wprep_kernel(
    const float* __restrict__ Wq, const float* __restrict__ Wk, const float* __restrict__ Wv,
    unsigned short* __restrict__ Wt)
{
    const int m = blockIdx.y;
    const float* W = (m == 0) ? Wq : (m == 1) ? Wk : Wv;
    unsigned short* Wo = Wt + (size_t)m * 64 * 1024;
    __shared__ unsigned short T[64][65];
    const int t = threadIdx.x;
    const int k0 = blockIdx.x * 64;
    #pragma unroll
    for (int i = 0; i < 16; i++) {
        int vi = t + i * 256;
        int kk = vi >> 6, n = vi & 63;
        T[kk][n] = f2bf(W[(size_t)(k0 + kk) * 64 + n]);
    }
    __syncthreads();
    #pragma unroll
    for (int i = 0; i < 4; i++) {
        int vi = t + i * 256;
        int n = vi >> 4, k4 = vi & 15;
        ushort4 u;
        u.x = T[k4*4+0][n]; u.y = T[k4*4+1][n]; u.z = T[k4*4+2][n]; u.w = T[k4*4+3][n];
        *(ushort4*)&Wo[(size_t)n * 1024 + k0 + k4*4] = u;
    }
}

// x[M,1024] @ W[1024,64]. Round-3 post-mortem: proj is bound by the per-CU
// vector-memory path (~26 B/cy/CU); L3-resident replays still took 94 us.
// Register-B re-read the whole 128KB Wt PER WAVE (402 MB of L2 traffic).
// Hybrid: A streams through a 4-deep REGISTER pipeline (zero reuse, no
// barriers); B is staged to LDS once per BLOCK per 32-k chunk (4KB), cutting
// total vector-path bytes 603->300 MB. Quad-buffered B + counted vmcnt(8)
// keeps ~2.5 chunks of loads in flight ACROSS the per-chunk barrier.
// Issue order per region is pinned by empty memory-clobber asm so the
// counted vmcnt is exact: region kc issues [B(kc+3); A(kc+4)]; after B(kc)
// come A(kc+1),B(kc+1),A(kc+2),B(kc+2),A(kc+3) = 8 vmem -> vmcnt(8).
// First region drains (vmcnt 0) since prologue order is pinned but cheap.
// B LDS is 16B-unit swizzled: unit u of row n holds source k-unit u^(n&3)
// (involution; read applies same XOR). Banks balanced: 8 lanes per 4-bank
// group, every bank serves 8 dwords per b128 read.
__global__ __launch_bounds__(256) void proj_kernel(
    const float* __restrict__ q, const float* __restrict__ kx, const float* __restrict__ vx,
    const unsigned short* __restrict__ Wt,
    unsigned short* __restrict__ qp, unsigned short* __restrict__ kp, unsigned short* __restrict__ vpT)
{
    __shared__ unsigned short Bb[4][64 * 32];   // 4 x 4KB chunk buffers

    const int m = blockIdx.y;
    const float* x = (m == 0) ? q : (m == 1) ? kx : vx;
    const unsigned short* Wm = Wt + (size_t)m * 64 * 1024;

    const int t = threadIdx.x;
    const int w = t >> 6, l = t & 63;
    const int lrow = l & 15, quad = l >> 4;
    const int row0 = blockIdx.x * 64;

    // A stream: row = row0 + w*16 + lrow, k-offset quad*8 within each 32-chunk
    const float* xa = x + (size_t)(row0 + w * 16 + lrow) * D_ + quad * 8;

    // B stage: thread t -> row n = t>>2, 16B unit u = t&3; source k pre-swizzled.
    const int bn = t >> 2, bu = t & 3;
    const unsigned short* wsrc = Wm + (size_t)bn * 1024 + (bu ^ (bn & 3)) * 8;

    // B read: unit swizzle is uniform in c (n = c*16+lrow -> n&3 == lrow&3)
    const int runit = (quad ^ (lrow & 3)) * 8;

    f32x4 acc[4] = {};
    f32x4 pa0[4], pa1[4];

#define ISSUE_B(kc, buf) do { \
    async16(wsrc + (kc) * 32, &Bb[buf][t * 8]); \
    asm volatile("" ::: "memory"); } while (0)

#define LOAD_A(st, kc) do { \
    pa0[st] = *(const f32x4*)(xa + (kc) * 32); \
    pa1[st] = *(const f32x4*)(xa + (kc) * 32 + 4); \
    asm volatile("" ::: "memory"); } while (0)

#define COMPUTE(st, buf) do { \
    f32x4 a0_ = pa0[st], a1_ = pa1[st]; \
    bf16x8 af_; \
    af_[0] = (short)f2bf(a0_.x); af_[1] = (short)f2bf(a0_.y); \
    af_[2] = (short)f2bf(a0_.z); af_[3] = (short)f2bf(a0_.w); \
    af_[4] = (short)f2bf(a1_.x); af_[5] = (short)f2bf(a1_.y); \
    af_[6] = (short)f2bf(a1_.z); af_[7] = (short)f2bf(a1_.w); \
    bf16x8 b0_ = *(const bf16x8*)&Bb[buf][0 * 512 + lrow * 32 + runit]; \
    bf16x8 b1_ = *(const bf16x8*)&Bb[buf][1 * 512 + lrow * 32 + runit]; \
    bf16x8 b2_ = *(const bf16x8*)&Bb[buf][2 * 512 + lrow * 32 + runit]; \
    bf16x8 b3_ = *(const bf16x8*)&Bb[buf][3 * 512 + lrow * 32 + runit]; \
    acc[0] = __builtin_amdgcn_mfma_f32_16x16x32_bf16(af_, b0_, acc[0], 0, 0, 0); \
    acc[1] = __builtin_amdgcn_mfma_f32_16x16x32_bf16(af_, b1_, acc[1], 0, 0, 0); \
    acc[2] = __builtin_amdgcn_mfma_f32_16x16x32_bf16(af_, b2_, acc[2], 0, 0, 0); \
    acc[3] = __builtin_amdgcn_mfma_f32_16x16x32_bf16(af_, b3_, acc[3], 0, 0, 0); } while (0)

    // prologue: B chunks 0..2, A chunks 0..3 (order pinned by the fences)
    ISSUE_B(0, 0); LOAD_A(0, 0);
    ISSUE_B(1, 1); LOAD_A(1, 1);
    ISSUE_B(2, 2); LOAD_A(2, 2);
    LOAD_A(3, 3);

    // kc = 0: full drain once (prologue counted-wait not worth the fragility)
    asm volatile("s_waitcnt vmcnt(0)\n\ts_barrier" ::: "memory");
    ISSUE_B(3, 3);
    COMPUTE(0, 0);
    LOAD_A(0, 4);

    // kc = 1..24 (6 outer x 4 inner; stage/buffer index = kc&3 compile-time)
    #pragma unroll 1
    for (int ob = 0; ob < 6; ++ob) {
        const int kb = ob * 4 + 1;
        #pragma unroll
        for (int kk = 0; kk < 4; ++kk) {
            const int kc = kb + kk;          // 1..24
            const int st = (kk + 1) & 3;     // == kc&3
            asm volatile("s_waitcnt vmcnt(8)\n\ts_barrier" ::: "memory");
            ISSUE_B(kc + 3, (st + 3) & 3);
            COMPUTE(st, st);
            LOAD_A(st, kc + 4);
        }
    }
    // kc = 25, 26, 27 (A refills 29..31; B issues 28..30)
    asm volatile("s_waitcnt vmcnt(8)\n\ts_barrier" ::: "memory");
    ISSUE_B(28, 0); COMPUTE(1, 1); LOAD_A(1, 29);
    asm volatile("s_waitcnt vmcnt(8)\n\ts_barrier" ::: "memory");
    ISSUE_B(29, 1); COMPUTE(2, 2); LOAD_A(2, 30);
    asm volatile("s_waitcnt vmcnt(8)\n\ts_barrier" ::: "memory");
    ISSUE_B(30, 2); COMPUTE(3, 3); LOAD_A(3, 31);
    // kc = 28: last B issue
    asm volatile("s_waitcnt vmcnt(8)\n\ts_barrier" ::: "memory");
    ISSUE_B(31, 3);
    COMPUTE(0, 0);
    // kc = 29..31: everything resident after one drain
    asm volatile("s_waitcnt vmcnt(0)\n\ts_barrier" ::: "memory");
    COMPUTE(1, 1);
    COMPUTE(2, 2);
    COMPUTE(3, 3);

#undef ISSUE_B
#undef LOAD_A
#undef COMPUTE

    const int orow = row0 + w * 16 + quad * 4;
    if (m < 2) {
        unsigned short* outp = (m == 0) ? qp : kp;
        const float sc = (m == 0) ? 0.125f : 1.0f;   // fold attn scale into qp
        #pragma unroll
        for (int c = 0; c < 4; c++)
            #pragma unroll
            for (int rr = 0; rr < 4; rr++)
                outp[(size_t)(orow + rr) * H_ + c * 16 + lrow] = f2bf(acc[c][rr] * sc);
    } else {
        // vpT[b][h][s], s0..s0+3 contiguous per lane -> 8B stores
        const int bb = orow >> 11;
        const int s0 = orow & (S_ - 1);
        #pragma unroll
        for (int c = 0; c < 4; c++) {
            ushort4 u;
            u.x = f2bf(acc[c][0]); u.y = f2bf(acc[c][1]);
            u.z = f2bf(acc[c][2]); u.w = f2bf(acc[c][3]);
            *(ushort4*)&vpT[((size_t)bb * H_ + c * 16 + lrow) * S_ + s0] = u;
        }
    }
}

// Flash attention partial: block = (q-tile 64, batch, key-split). Max-free
// single-pass exp => partials over disjoint key ranges combine by addition.
// K and V^T tiles async-staged (L2-resident -> cheap barrier drain).
__global__ __launch_bounds__(256) void attn_kernel(
    const unsigned short* __restrict__ qp, const unsigned short* __restrict__ kp,
    const unsigned short* __restrict__ vpT, const float* __restrict__ mmul,
    float* __restrict__ po, float* __restrict__ pl)
{
    __shared__ unsigned short Qs[64][72];
    __shared__ unsigned short Ps[64][72];
    __shared__ unsigned short Ks[64 * 64];   // swizzled chunks [key][h]
    __shared__ unsigned short Vt[64 * 64];   // swizzled chunks [h][key]

    const int t = threadIdx.x;
    const int w = t >> 6, l = t & 63;
    const int lrow = l & 15, quad = l >> 4;
    const int b = blockIdx.y, q0 = blockIdx.x * 64, split = blockIdx.z;
    const int key0 = split * KPS;
    const size_t basebs = (size_t)b * S_;
    const unsigned short* vb = vpT + (size_t)b * H_ * S_;

    #pragma unroll
    for (int i = 0; i < 2; i++) {            // Q tile once: 512 16B-chunks
        int p = t + i * 256;
        int r = p >> 3, c8 = p & 7;
        u16x8 u = *(const u16x8*)&qp[(basebs + q0 + r) * H_ + c8 * 8];
        *(u16x8*)&Qs[r][c8 * 8] = u;
    }

    float lsum[4] = {0.f, 0.f, 0.f, 0.f};
    f32x4 o[4] = {};

    for (int kt = 0; kt < KPS / 64; kt++) {
        const int k0 = key0 + kt * 64;
        __syncthreads();                     // prev tile's LDS reads done
        #pragma unroll
        for (int j = 0; j < 2; j++) {        // K tile: 512 chunks
            int p = (w * 2 + j) * 64 + l;
            int r = p >> 3;
            int c8 = (p & 7) ^ (r & 7);
            async16(&kp[(basebs + k0 + r) * H_ + c8 * 8], &Ks[p * 8]);
        }
        #pragma unroll
        for (int j = 0; j < 2; j++) {        // V^T tile: 512 chunks
            int p = (w * 2 + j) * 64 + l;
            int h = p >> 3;
            int c8 = (p & 7) ^ (h & 7);
            async16(&vb[(size_t)h * S_ + k0 + c8 * 8], &Vt[p * 8]);
        }
        float mm[4];
        #pragma unroll
        for (int c = 0; c < 4; c++) mm[c] = mmul[basebs + k0 + c*16 + lrow];
        __syncthreads();                     // drain async queue

        // S = Q K^T (pre-scaled by 1/8 via qp)
        f32x4 s[4] = {};
        #pragma unroll
        for (int kk = 0; kk < 2; kk++) {
            bf16x8 aq = *(const bf16x8*)&Qs[w*16 + lrow][kk*32 + quad*8];
            #pragma unroll
            for (int c = 0; c < 4; c++) {
                const int n = c*16 + lrow;
                bf16x8 bk = *(const bf16x8*)&Ks[(n * 8 + ((kk*4 + quad) ^ (n & 7))) * 8];
                s[c] = __builtin_amdgcn_mfma_f32_16x16x32_bf16(aq, bk, s[c], 0, 0, 0);
            }
        }
        // single-pass softmax numerator; sum deferred
        #pragma unroll
        for (int r = 0; r < 4; r++) {
            float p0 = __expf(s[0][r]) * mm[0];
            float p1 = __expf(s[1][r]) * mm[1];
            float p2 = __expf(s[2][r]) * mm[2];
            float p3 = __expf(s[3][r]) * mm[3];
            lsum[r] += (p0 + p1) + (p2 + p3);
            const int pr = w*16 + quad*4 + r;
            Ps[pr][ 0 + lrow] = f2bf(p0);
            Ps[pr][16 + lrow] = f2bf(p1);
            Ps[pr][32 + lrow] = f2bf(p2);
            Ps[pr][48 + lrow] = f2bf(p3);
        }
        // Ps rows [w*16, w*16+16) wave-local: no barrier needed
        #pragma unroll
        for (int kk = 0; kk < 2; kk++) {
            bf16x8 ap = *(const bf16x8*)&Ps[w*16 + lrow][kk*32 + quad*8];
            #pragma unroll
            for (int c = 0; c < 4; c++) {
                const int h = c*16 + lrow;
                bf16x8 bv = *(const bf16x8*)&Vt[(h * 8 + ((kk*4 + quad) ^ (h & 7))) * 8];
                o[c] = __builtin_amdgcn_mfma_f32_16x16x32_bf16(ap, bv, o[c], 0, 0, 0);
            }
        }
    }

    float* pob = po + (size_t)split * M_ * H_;
    float* plb = pl + (size_t)split * M_;
    #pragma unroll
    for (int r = 0; r < 4; r++) {
        #pragma unroll
        for (int d = 1; d < 16; d <<= 1)
            lsum[r] += __shfl_xor(lsum[r], d, 64);
        const size_t row = basebs + q0 + w*16 + quad*4 + r;
        if (lrow == 0) plb[row] = lsum[r];
        #pragma unroll
        for (int c = 0; c < 4; c++)
            pob[row * H_ + c*16 + lrow] = o[c][r];
    }
}

// out = (sum_s po[s]) / (sum_s pl[s]); one float4 per thread.
__global__ __launch_bounds__(256) void combine_kernel(
    const float* __restrict__ po, const float* __restrict__ pl, float* __restrict__ out)
{
    const int idx = blockIdx.x * 256 + threadIdx.x;
    const size_t row = idx >> 4;
    const int c4 = (idx & 15) * 4;
    float lt = 0.f;
    #pragma unroll
    for (int s = 0; s < SPLIT; s++) lt += pl[(size_t)s * M_ + row];
    f32x4 acc = {};
    #pragma unroll
    for (int s = 0; s < SPLIT; s++) {
        const f32x4 p = *(const f32x4*)&po[((size_t)s * M_ + row) * H_ + c4];
        acc += p;
    }
    const float inv = 1.0f / lt;
    f32x4 r = acc * inv;
    *(f32x4*)&out[row * H_ + c4] = r;
}

extern "C" void kernel_launch(void* const* d_in, const int* in_sizes, int n_in,
                              void* d_out, int out_size, void* d_ws, size_t ws_size,
                              hipStream_t stream) {
    const float* q  = (const float*)d_in[0];
    const float* k  = (const float*)d_in[1];
    const float* v  = (const float*)d_in[2];
    const unsigned char* mask = (const unsigned char*)d_in[3];
    const float* Wq = (const float*)d_in[4];
    const float* Wk = (const float*)d_in[5];
    const float* Wv = (const float*)d_in[6];
    float* out = (float*)d_out;

    unsigned short* qp  = (unsigned short*)d_ws;         // 2 MB
    unsigned short* kp  = qp + (size_t)M_ * H_;          // 2 MB
    unsigned short* vpT = kp + (size_t)M_ * H_;          // 2 MB, [b][h][s]
    float* mmul = (float*)(vpT + (size_t)M_ * H_);       // 64 KB
    unsigned short* Wt = (unsigned short*)(mmul + M_);   // 384 KB
    float* po = (float*)(Wt + (size_t)3 * 64 * 1024);    // 16.8 MB
    float* pl = po + (size_t)SPLIT * M_ * H_;            // 256 KB

    wprep_kernel<<<dim3(16, 3), dim3(256), 0, stream>>>(Wq, Wk, Wv, Wt);
    mask_kernel<<<dim3((M_ + 255)/256), dim3(256), 0, stream>>>(mask, mmul, M_);
    proj_kernel<<<dim3(M_/64, 3), dim3(256), 0, stream>>>(q, k, v, Wt, qp, kp, vpT);
    attn_kernel<<<dim3(S_/64, B_, SPLIT), dim3(256), 0, stream>>>(qp, kp, vpT, mmul, po, pl);
    combine_kernel<<<dim3(M_*16/256), dim3(256), 0, stream>>>(po, pl, out);
}